// Round 5
// baseline (3063.500 us; speedup 1.0000x reference)
//
#include <hip/hip_runtime.h>
#include <math.h>

// ---------------------------------------------------------------------------
// TDS decoder R5: persistent kernel, 64 blocks x 1024 threads (128 rows/blk).
// Handshake: single-writer per-block regions with an in-region TAG word
// published by a RELEASE store (tag fresh => data at MALL). Consumers load
// data+tag together: poll and gather are one leg. No atomics, no counters,
// no zeroing (3-slot rotation; 0xAA poison never matches a tag).
// Region (96 floats, 64B-aligned): f0..40 = logit partial (+S@40),
// f41 = hp, f42..62 spare, f63 = tag(int t+1), f64..87 = gh rows.
// ---------------------------------------------------------------------------

#define NV      40
#define TENC    8192
#define MAXLEN  200
#define EOS_IDX 38
#define NB      64
#define NT      1024
#define NW      16
#define ROWS    128                   /* attention rows per block (8/wave)  */
#define RS      96                    /* region stride (floats)             */
#define SLOTF   (NB * RS)             /* 6144 floats per rotation slot      */
#define SCALE   0.04419417382415922f  /* 1/sqrt(512) */

#define WS_REG  0                     /* float[3][SLOTF]                    */
#define WS_GI   (3 * SLOTF)           /* 18432: float[40*1536]              */

__device__ __forceinline__ int ld_ai(const int* p) {
  return __hip_atomic_load(p, __ATOMIC_RELAXED, __HIP_MEMORY_SCOPE_AGENT);
}
__device__ __forceinline__ float ld_af(const float* p) {
  return __hip_atomic_load(p, __ATOMIC_RELAXED, __HIP_MEMORY_SCOPE_AGENT);
}
__device__ __forceinline__ void st_af(float* p, float v) {
  __hip_atomic_store(p, v, __ATOMIC_RELAXED, __HIP_MEMORY_SCOPE_AGENT);
}
__device__ __forceinline__ int ld_lds_acq(int* p) {
  return __hip_atomic_load(p, __ATOMIC_ACQUIRE, __HIP_MEMORY_SCOPE_WORKGROUP);
}
__device__ __forceinline__ void st_lds_rel(int* p, int v) {
  __hip_atomic_store(p, v, __ATOMIC_RELEASE, __HIP_MEMORY_SCOPE_WORKGROUP);
}

__device__ __forceinline__ float wred(float s) {
#pragma unroll
  for (int o = 32; o > 0; o >>= 1) s += __shfl_xor(s, o, 64);
  return s;
}
__device__ __forceinline__ float dot8(float4 a0, float4 a1, float4 b0,
                                      float4 b1) {
  return a0.x * b0.x + a0.y * b0.y + a0.z * b0.z + a0.w * b0.w +
         a1.x * b1.x + a1.y * b1.y + a1.z * b1.z + a1.w * b1.w;
}
__device__ __forceinline__ float wdot512(const float* __restrict__ a,
                                         const float* __restrict__ b) {
  const int l = threadIdx.x & 63;
  const float4 a0 = ((const float4*)a)[l];
  const float4 a1 = ((const float4*)a)[l + 64];
  const float4 b0 = ((const float4*)b)[l];
  const float4 b1 = ((const float4*)b)[l + 64];
  return wred(dot8(a0, a1, b0, b1));
}

__global__ void __launch_bounds__(NT, 4) dec_main(
    const float* __restrict__ enc, const float* __restrict__ hidden,
    const float* __restrict__ embed, const float* __restrict__ w_ih,
    const float* __restrict__ w_hh, const float* __restrict__ b_ih,
    const float* __restrict__ b_hh, const float* __restrict__ w_out,
    const float* __restrict__ b_out, float* __restrict__ o,
    float* __restrict__ ws) {
  const int b = blockIdx.x, tid = threadIdx.x;
  const int wave = tid >> 6, lane = tid & 63;
  const int r0 = b * ROWS;

  __shared__ __align__(16) float h_lds[512];
  __shared__ float p_lds[2][ROWS];     // attention weights, ping-pong
  __shared__ float pwg_lds[4 * 64];    // gather-wave partials
  __shared__ float pw_lds[NW * 64];    // dot-wave fold partials
  __shared__ float hp_lds[NV];
  __shared__ float stage_gh[24];
  __shared__ float stage_hp[1];
  __shared__ float sc_lds[1];
  __shared__ int gcnt;                 // monotonic gather counter
  __shared__ int bf_lds;               // (t<<6)|best

  // ----------------- prologue -----------------
  if (tid < 512) h_lds[tid] = hidden[tid];
  if (tid == 0) { gcnt = 0; bf_lds = -1; }

  // gi_all[v][j] = W_ih[j].embed[v] + b_ih[j]  (960 dots per block)
  for (int u = wave; u < 960; u += NW) {
    const int gl = b * 960 + u;
    const int v = gl / 1536, j = gl - v * 1536;
    const float d = wdot512(w_ih + (size_t)j * 512, embed + (size_t)v * 512);
    if (lane == 0) st_af(&ws[WS_GI + (size_t)v * 1536 + j], d + b_ih[j]);
  }
  // gh(h0): 24 rows per block -> stage
  for (int jr = wave; jr < 24; jr += NW) {
    const int j = b * 24 + jr;
    const float d = wdot512(w_hh + (size_t)j * 512, hidden);
    if (lane == 0) stage_gh[jr] = d + b_hh[j];
  }
  __syncthreads();  // drains every wave's gi stores (vmcnt 0 before barrier)
  if (wave == 0) {  // publish prologue region: slot 2, tag 0 (gh only)
    float* out = ws + WS_REG + 2 * SLOTF + b * RS;
    if (lane < 24) st_af(out + 64 + lane, stage_gh[lane]);
    if (lane == 0)
      __hip_atomic_store((int*)(out + 63), 0, __ATOMIC_RELEASE,
                         __HIP_MEMORY_SCOPE_AGENT);
  }

  // --- register-resident K rows and M columns (after publish) ---
  float4 ka[8], kb[8];
#pragma unroll
  for (int i = 0; i < 8; ++i) {
    const float* kp = enc + (size_t)(r0 + 8 * wave + i) * 1024;
    ka[i] = ((const float4*)kp)[lane];
    kb[i] = ((const float4*)kp)[lane + 64];
  }
  float Mr[8];  // Mr[i][lane<40] = W_out[lane,:512].V[row_i]; lane40 = 1
#pragma unroll
  for (int i = 0; i < 8; ++i) {
    const float* vp = enc + (size_t)(r0 + 8 * wave + i) * 1024 + 512;
    const float4 va = ((const float4*)vp)[lane];
    const float4 vb = ((const float4*)vp)[lane + 64];
    float m = (lane == 40) ? 1.0f : 0.0f;
    for (int v = 0; v < NV; ++v) {
      const float* wp = w_out + (size_t)v * 1024;
      const float4 w0 = ((const float4*)wp)[lane];
      const float4 w1 = ((const float4*)wp)[lane + 64];
      const float s = wred(dot8(va, vb, w0, w1));
      if (lane == v) m = s;
    }
    Mr[i] = m;
  }

  // GRU thread source offsets (j, j+512, j+1024 from 3 regions)
  int t0o = 0, v0o = 0, t1o = 0, v1o = 0, t2o = 0, v2o = 0;
  if (tid >= 512) {
    const int j = tid - 512;
    const int g0 = j / 24, i0 = j % 24;
    const int g1 = (j + 512) / 24, i1 = (j + 512) % 24;
    const int g2 = (j + 1024) / 24, i2 = (j + 1024) % 24;
    t0o = g0 * RS + 63; v0o = g0 * RS + 64 + i0;
    t1o = g1 * RS + 63; v1o = g1 * RS + 64 + i1;
    t2o = g2 * RS + 63; v2o = g2 * RS + 64 + i2;
  }

  // ----------------- main loop -----------------
  int eos_reg = -1;  // block0/wave0/lane0 only
  float* attn = o + (size_t)MAXLEN * NV + 1;

  for (int t = 0; t <= MAXLEN; ++t) {
    float* sbase = ws + WS_REG + ((t + 2) % 3) * SLOTF;  // slot (t-1)%3, tag t

    if (wave < 4) {
      // ---- combined poll+gather: 16 regions per wave, sticky ----
      unsigned undone = 0xFFFFu;
      float cs = 0.0f, hpv = 0.0f;
      while (undone) {
        unsigned m = undone;
        while (m) {
          const int r = __ffs(m) - 1;
          m &= m - 1;
          const int g = 16 * wave + r;
          const float x = ld_af(sbase + g * RS + lane);
          const int tg = __float_as_int(__shfl(x, 63));
          if (tg == t) {  // wave-uniform
            if (t > 0) {
              if (lane <= 40) cs += x;
              const float h41 = __shfl(x, 41);
              if (lane == g - 1) hpv = h41;
            }
            undone &= ~(1u << r);
          }
        }
        if (undone) __builtin_amdgcn_s_sleep(1);
      }
      if (t > 0) {
        pwg_lds[wave * 64 + lane] = cs;
        if (lane >= 16 * wave - 1 && lane <= 16 * wave + 14 && lane < NV)
          hp_lds[lane] = hpv;
      }
      if (lane == 0)
        __hip_atomic_fetch_add(&gcnt, 1, __ATOMIC_RELEASE,
                               __HIP_MEMORY_SCOPE_WORKGROUP);
      if (wave == 0) {
        while (ld_lds_acq(&gcnt) < 4 * (t + 1)) __builtin_amdgcn_s_sleep(1);
        if (t > 0) {
          const float cs4 = pwg_lds[lane] + pwg_lds[64 + lane] +
                            pwg_lds[128 + lane] + pwg_lds[192 + lane];
          const float S = __shfl(cs4, 40);
          const float hp = (lane < NV) ? hp_lds[lane] : 0.0f;
          const float ov = cs4 * (1.0f / S) + hp;
          unsigned long long key = 0ull;
          if (lane < NV) {
            unsigned u = __float_as_uint(ov);
            u = (u & 0x80000000u) ? ~u : (u | 0x80000000u);
            key = ((unsigned long long)u << 32) | (unsigned)(~lane);
          }
#pragma unroll
          for (int mm = 32; mm > 0; mm >>= 1) {
            const unsigned long long k2 = __shfl_xor(key, mm, 64);
            if (k2 > key) key = k2;
          }
          const int best = (int)(~(unsigned)key);
          if (lane == 0) sc_lds[0] = S;
          if (b == 0 && lane < NV) o[(size_t)(t - 1) * NV + lane] = ov;
          if (b == 0 && lane == 0) {
            if (best == EOS_IDX && eos_reg < 0) eos_reg = t - 1;
            if (t == MAXLEN)
              o[(size_t)MAXLEN * NV] =
                  (eos_reg < 0) ? (float)MAXLEN : (float)eos_reg;
          }
          if (lane == 0) st_lds_rel(&bf_lds, (t << 6) | best);
        } else if (lane == 0) {
          st_lds_rel(&bf_lds, EOS_IDX);  // (0<<6)|EOS
        }
      }
    } else if (wave >= 8 && t < MAXLEN) {
      // ---- GRU: self-poll 3 gh tags (overlaps wave0 gather) ----
      const int j = tid - 512;
      float ghr = 0.0f, ghz = 0.0f, ghn = 0.0f;
      bool d0 = false, d1 = false, d2 = false;
      for (;;) {
        if (!d0 && ld_ai((int*)(sbase + t0o)) == t) {
          ghr = ld_af(sbase + v0o);
          d0 = true;
        }
        if (!d1 && ld_ai((int*)(sbase + t1o)) == t) {
          ghz = ld_af(sbase + v1o);
          d1 = true;
        }
        if (!d2 && ld_ai((int*)(sbase + t2o)) == t) {
          ghn = ld_af(sbase + v2o);
          d2 = true;
        }
        if (d0 && d1 && d2) break;
        __builtin_amdgcn_s_sleep(1);
      }
      int bf;
      while (((bf = ld_lds_acq(&bf_lds)) >> 6) < t) __builtin_amdgcn_s_sleep(1);
      const float* gi = ws + WS_GI + (size_t)(bf & 63) * 1536;
      const float gir = gi[j], giz = gi[j + 512], gin = gi[j + 1024];
      const float r = 1.0f / (1.0f + expf(-(gir + ghr)));
      const float z = 1.0f / (1.0f + expf(-(giz + ghz)));
      const float n = tanhf(gin + r * ghn);
      h_lds[j] = (1.0f - z) * n + z * h_lds[j];
    }
    __syncthreads();  // barrier A: h_t, sc_lds, p ping-pong ready

    // previous step's normalized attention weights
    if (t > 0 && tid < ROWS)
      attn[(size_t)(t - 1) * TENC + r0 + tid] =
          p_lds[(t + 1) & 1][tid] * (1.0f / sc_lds[0]);
    if (t == MAXLEN) break;

    // ---- dots: 8 K-dots per wave (K, M in regs); aux rows from L1/L2 ----
    {
      const float4 hh0 = ((const float4*)h_lds)[lane];
      const float4 hh1 = ((const float4*)h_lds)[lane + 64];
      float pw = 0.0f;
#pragma unroll
      for (int i = 0; i < 8; ++i) {
        const float d = wred(dot8(ka[i], kb[i], hh0, hh1));
        const float p = expf(d * SCALE);
        if (lane == 0) p_lds[t & 1][wave * 8 + i] = p;
        pw += p * Mr[i];
      }
      if (lane <= 40) pw_lds[wave * 64 + lane] = pw;
      if (wave >= 1 && wave <= 6) {  // gh_t rows (4 per wave)
#pragma unroll
        for (int q = 0; q < 4; ++q) {
          const int jr = (wave - 1) * 4 + q;
          const float* wp = w_hh + (size_t)(b * 24 + jr) * 512;
          const float4 a0 = ((const float4*)wp)[lane];
          const float4 a1 = ((const float4*)wp)[lane + 64];
          const float d = wred(dot8(a0, a1, hh0, hh1));
          if (lane == 0) stage_gh[jr] = d + b_hh[b * 24 + jr];
        }
      } else if (wave == 7 && b >= 1 && b <= NV) {  // hp row
        const float* wp = w_out + (size_t)(b - 1) * 1024 + 512;
        const float4 a0 = ((const float4*)wp)[lane];
        const float4 a1 = ((const float4*)wp)[lane + 64];
        const float d = wred(dot8(a0, a1, hh0, hh1));
        if (lane == 0) stage_hp[0] = d + b_out[b - 1];
      }
    }
    __syncthreads();  // barrier C: pw/stage complete

    // ---- wave0: pack region, publish with release tag ----
    if (wave == 0) {
      float red = 0.0f;
      if (lane <= 40) {
#pragma unroll
        for (int w2 = 0; w2 < NW; ++w2) red += pw_lds[w2 * 64 + lane];
      }
      const float hpval = (b >= 1 && b <= NV) ? stage_hp[0] : 0.0f;
      float* out = ws + WS_REG + (t % 3) * SLOTF + b * RS;
      const float val = (lane <= 40) ? red : ((lane == 41) ? hpval : 0.0f);
      if (lane != 63) st_af(out + lane, val);
      if (lane < 24) st_af(out + 64 + lane, stage_gh[lane]);
      if (lane == 0)
        __hip_atomic_store((int*)(out + 63), t + 1, __ATOMIC_RELEASE,
                           __HIP_MEMORY_SCOPE_AGENT);
    }
  }
}

extern "C" void kernel_launch(void* const* d_in, const int* in_sizes, int n_in,
                              void* d_out, int out_size, void* d_ws,
                              size_t ws_size, hipStream_t stream) {
  const float* enc    = (const float*)d_in[0];
  const float* hidden = (const float*)d_in[1];
  const float* embed  = (const float*)d_in[2];
  const float* w_ih   = (const float*)d_in[3];
  const float* w_hh   = (const float*)d_in[4];
  const float* b_ih   = (const float*)d_in[5];
  const float* b_hh   = (const float*)d_in[6];
  const float* w_out  = (const float*)d_in[7];
  const float* b_out  = (const float*)d_in[8];
  float* out = (float*)d_out;
  float* ws  = (float*)d_ws;

  dec_main<<<dim3(NB), dim3(NT), 0, stream>>>(enc, hidden, embed, w_ih, w_hh,
                                              b_ih, b_hh, w_out, b_out, out,
                                              ws);
}